// Round 7
// baseline (193.191 us; speedup 1.0000x reference)
//
#include <hip/hip_runtime.h>
#include <math.h>

// ---------------------------------------------------------------------------
// Kernel A: per-image conv1+pool, conv2+pool, fc1 -> h1 [1024][128] in ws.
// ---------------------------------------------------------------------------
__global__ __launch_bounds__(256) void k_body(
    const float* __restrict__ x,
    const float* __restrict__ c1w, const float* __restrict__ c1b,
    const float* __restrict__ c2w, const float* __restrict__ c2b,
    const float* __restrict__ fc1w, const float* __restrict__ fc1b,
    float* __restrict__ h1g)
{
    __shared__ __align__(16) float p1[32*288];   // [ic][16 rows][18 cols], zero border
    __shared__ __align__(16) float p2[3136];     // union: img(900) during conv1, then p2

    const int b = blockIdx.x, t = threadIdx.x;
    const int lane = t & 63, wv = t >> 6;
    const int p  = lane < 49 ? lane : 48;        // conv2 pooled position (7x7)
    const int py = p / 7, px = p % 7;

    for (int i = t; i < 9216; i += 256) p1[i] = 0.f;
    float* img = p2;                              // 30x30 padded, stride 30
    for (int i = t; i < 900; i += 256) img[i] = 0.f;
    __syncthreads();
    const float* xi = x + (size_t)b * 784;
    for (int i = t; i < 784; i += 256)
        img[(i/28 + 1)*30 + (i%28 + 1)] = xi[i];
    __syncthreads();

    // ---- conv1 (1->32) + ReLU + maxpool2 -> p1 ----
    {
        const int ocb1 = __builtin_amdgcn_readfirstlane(wv*8);
        float wk[8][9], bv[8];
        #pragma unroll
        for (int o = 0; o < 8; ++o) {
            bv[o] = c1b[ocb1 + o];
            #pragma unroll
            for (int k = 0; k < 9; ++k) wk[o][k] = c1w[(ocb1 + o)*9 + k];
        }
        #pragma unroll
        for (int ch = 0; ch < 4; ++ch) {
            int pos = ch*64 + lane;
            const bool act = pos < 196;
            if (!act) pos = 195;
            const int qy = pos / 14, qx = pos % 14;
            const float* ib = img + (2*qy)*30 + 2*qx;
            float v[4][4];
            #pragma unroll
            for (int rr = 0; rr < 4; ++rr) {
                const float2 a = *(const float2*)(ib + rr*30);
                const float2 c = *(const float2*)(ib + rr*30 + 2);
                v[rr][0]=a.x; v[rr][1]=a.y; v[rr][2]=c.x; v[rr][3]=c.y;
            }
            #pragma unroll
            for (int o = 0; o < 8; ++o) {
                float m = 0.f;                    // relu(max) == max(0, max)
                #pragma unroll
                for (int dy = 0; dy < 2; ++dy)
                #pragma unroll
                for (int dx = 0; dx < 2; ++dx) {
                    float acc = bv[o];
                    #pragma unroll
                    for (int ky = 0; ky < 3; ++ky)
                    #pragma unroll
                    for (int kx = 0; kx < 3; ++kx)
                        acc = fmaf(v[dy+ky][dx+kx], wk[o][ky*3+kx], acc);
                    m = fmaxf(m, acc);
                }
                if (act) p1[(ocb1 + o)*288 + (qy+1)*18 + (qx+1)] = m;
            }
        }
    }
    __syncthreads();                              // img dead after this point

    // ---- conv2 (32->64) + ReLU + maxpool2 -> p2 ----
    for (int g = 0; g < 2; ++g) {
        const int ocb = __builtin_amdgcn_readfirstlane(g*32 + wv*8);
        float acc[8][2][2];
        #pragma unroll
        for (int o = 0; o < 8; ++o) {
            const float bvv = c2b[ocb + o];
            acc[o][0][0]=bvv; acc[o][0][1]=bvv; acc[o][1][0]=bvv; acc[o][1][1]=bvv;
        }
        #pragma unroll 4
        for (int ic = 0; ic < 32; ++ic) {
            const float* pp = p1 + ic*288 + (2*py)*18 + 2*px;
            float v[4][4];
            #pragma unroll
            for (int rr = 0; rr < 4; ++rr) {
                const float2 a = *(const float2*)(pp + rr*18);
                const float2 c = *(const float2*)(pp + rr*18 + 2);
                v[rr][0]=a.x; v[rr][1]=a.y; v[rr][2]=c.x; v[rr][3]=c.y;
            }
            const float* wb = c2w + (size_t)ocb*288 + ic*9;
            #pragma unroll
            for (int o = 0; o < 8; ++o) {
                float wk2[9];
                #pragma unroll
                for (int k = 0; k < 9; ++k) wk2[k] = wb[o*288 + k];
                #pragma unroll
                for (int dy = 0; dy < 2; ++dy)
                #pragma unroll
                for (int dx = 0; dx < 2; ++dx)
                    #pragma unroll
                    for (int ky = 0; ky < 3; ++ky)
                    #pragma unroll
                    for (int kx = 0; kx < 3; ++kx)
                        acc[o][dy][dx] = fmaf(v[dy+ky][dx+kx], wk2[ky*3+kx],
                                              acc[o][dy][dx]);
            }
        }
        if (lane < 49) {
            #pragma unroll
            for (int o = 0; o < 8; ++o) {
                const float mx = fmaxf(fmaxf(acc[o][0][0], acc[o][0][1]),
                                       fmaxf(acc[o][1][0], acc[o][1][1]));
                p2[(ocb + o)*49 + p] = fmaxf(mx, 0.f);
            }
        }
    }
    __syncthreads();

    // ---- fc1 (3136 -> 128) + ReLU -> h1g ----
    for (int pass = 0; pass < 8; ++pass) {
        const int o = wv*32 + pass*4;
        const float* w0 = fc1w + (size_t)o*3136;
        float a0=0.f, a1=0.f, a2=0.f, a3=0.f;
        for (int kb = 0; kb < 3072; kb += 256) {
            const int k = kb + lane*4;
            const float4 pv = *(const float4*)&p2[k];
            const float4 q0 = *(const float4*)(w0 + k);
            const float4 q1 = *(const float4*)(w0 + 3136 + k);
            const float4 q2 = *(const float4*)(w0 + 6272 + k);
            const float4 q3 = *(const float4*)(w0 + 9408 + k);
            a0 = fmaf(pv.x,q0.x,fmaf(pv.y,q0.y,fmaf(pv.z,q0.z,fmaf(pv.w,q0.w,a0))));
            a1 = fmaf(pv.x,q1.x,fmaf(pv.y,q1.y,fmaf(pv.z,q1.z,fmaf(pv.w,q1.w,a1))));
            a2 = fmaf(pv.x,q2.x,fmaf(pv.y,q2.y,fmaf(pv.z,q2.z,fmaf(pv.w,q2.w,a2))));
            a3 = fmaf(pv.x,q3.x,fmaf(pv.y,q3.y,fmaf(pv.z,q3.z,fmaf(pv.w,q3.w,a3))));
        }
        if (lane < 16) {                           // tail 3072..3135
            const int k = 3072 + lane*4;
            const float4 pv = *(const float4*)&p2[k];
            const float4 q0 = *(const float4*)(w0 + k);
            const float4 q1 = *(const float4*)(w0 + 3136 + k);
            const float4 q2 = *(const float4*)(w0 + 6272 + k);
            const float4 q3 = *(const float4*)(w0 + 9408 + k);
            a0 = fmaf(pv.x,q0.x,fmaf(pv.y,q0.y,fmaf(pv.z,q0.z,fmaf(pv.w,q0.w,a0))));
            a1 = fmaf(pv.x,q1.x,fmaf(pv.y,q1.y,fmaf(pv.z,q1.z,fmaf(pv.w,q1.w,a1))));
            a2 = fmaf(pv.x,q2.x,fmaf(pv.y,q2.y,fmaf(pv.z,q2.z,fmaf(pv.w,q2.w,a2))));
            a3 = fmaf(pv.x,q3.x,fmaf(pv.y,q3.y,fmaf(pv.z,q3.z,fmaf(pv.w,q3.w,a3))));
        }
        #pragma unroll
        for (int s = 1; s < 64; s <<= 1) {
            a0 += __shfl_xor(a0, s);
            a1 += __shfl_xor(a1, s);
            a2 += __shfl_xor(a2, s);
            a3 += __shfl_xor(a3, s);
        }
        float* hg = h1g + (size_t)b*128;
        if (lane == ((o+0)&63)) hg[o+0] = fmaxf(a0 + fc1b[o+0], 0.f);
        if (lane == ((o+1)&63)) hg[o+1] = fmaxf(a1 + fc1b[o+1], 0.f);
        if (lane == ((o+2)&63)) hg[o+2] = fmaxf(a2 + fc1b[o+2], 0.f);
        if (lane == ((o+3)&63)) hg[o+3] = fmaxf(a3 + fc1b[o+3], 0.f);
    }
}

// ---------------------------------------------------------------------------
// Kernel B: tail. 16 samples/block, 16 threads/sample. fc2+ReLU, fc3+ReLU,
// 4-qubit circuit (amplitude per lane in 16-lane groups), fc4, log_softmax.
// ---------------------------------------------------------------------------
__global__ __launch_bounds__(256) void k_head(
    const float* __restrict__ h1,
    const float* __restrict__ fc2w, const float* __restrict__ fc2b,
    const float* __restrict__ fc3w, const float* __restrict__ fc3b,
    const float* __restrict__ qw,
    const float* __restrict__ fc4w, const float* __restrict__ fc4b,
    float* __restrict__ out)
{
    __shared__ float h1s[16][132];
    __shared__ float h2s[16][68];
    __shared__ float fs[16][16];
    __shared__ float zs[16][12];
    const int t = threadIdx.x;
    const int r = t >> 4, l = t & 15;
    const int b0 = blockIdx.x * 16;
    for (int i = t; i < 16*128; i += 256) h1s[i>>7][i&127] = h1[(size_t)b0*128 + i];
    __syncthreads();

    // fc2: each thread computes outputs o0..o0+3 of its row
    const int o0 = l*4;
    float a0 = fc2b[o0+0], a1 = fc2b[o0+1], a2 = fc2b[o0+2], a3 = fc2b[o0+3];
    #pragma unroll 4
    for (int k4 = 0; k4 < 32; ++k4) {
        const float4 h  = *(const float4*)&h1s[r][k4*4];
        const float4 w0 = *(const float4*)&fc2w[(o0+0)*128 + k4*4];
        const float4 w1 = *(const float4*)&fc2w[(o0+1)*128 + k4*4];
        const float4 w2 = *(const float4*)&fc2w[(o0+2)*128 + k4*4];
        const float4 w3 = *(const float4*)&fc2w[(o0+3)*128 + k4*4];
        a0 = fmaf(h.x,w0.x,fmaf(h.y,w0.y,fmaf(h.z,w0.z,fmaf(h.w,w0.w,a0))));
        a1 = fmaf(h.x,w1.x,fmaf(h.y,w1.y,fmaf(h.z,w1.z,fmaf(h.w,w1.w,a1))));
        a2 = fmaf(h.x,w2.x,fmaf(h.y,w2.y,fmaf(h.z,w2.z,fmaf(h.w,w2.w,a2))));
        a3 = fmaf(h.x,w3.x,fmaf(h.y,w3.y,fmaf(h.z,w3.z,fmaf(h.w,w3.w,a3))));
    }
    {
        float4 v = make_float4(fmaxf(a0,0.f), fmaxf(a1,0.f), fmaxf(a2,0.f), fmaxf(a3,0.f));
        *(float4*)&h2s[r][o0] = v;
    }
    __syncthreads();

    // fc3: thread computes feat[l]
    float facc = fc3b[l];
    #pragma unroll 4
    for (int k4 = 0; k4 < 16; ++k4) {
        const float4 h  = *(const float4*)&h2s[r][k4*4];
        const float4 wv = *(const float4*)&fc3w[l*64 + k4*4];
        facc = fmaf(h.x,wv.x,fmaf(h.y,wv.y,fmaf(h.z,wv.z,fmaf(h.w,wv.w,facc))));
    }
    const float feat = fmaxf(facc, 0.f);
    fs[r][l] = feat;

    // ---- quantum circuit: amplitude per lane (bit of qubit q is 3-q) ----
    float nrm2 = feat*feat;
    nrm2 += __shfl_xor(nrm2, 1);
    nrm2 += __shfl_xor(nrm2, 2);
    nrm2 += __shfl_xor(nrm2, 4);
    nrm2 += __shfl_xor(nrm2, 8);
    const float nrm = fmaxf(sqrtf(nrm2), 1e-12f);
    float re = feat / nrm, im = 0.f;
    #pragma unroll
    for (int layer = 0; layer < 2; ++layer) {
        #pragma unroll
        for (int q = 0; q < 4; ++q) {
            const float phi = qw[(layer*4 + q)*3 + 0];
            const float th  = qw[(layer*4 + q)*3 + 1];
            const float om  = qw[(layer*4 + q)*3 + 2];
            float st, ct; sincosf(0.5f*th, &st, &ct);
            float sa, ca; sincosf(0.5f*(phi + om), &sa, &ca);   // ep = ca - i sa
            float sb, cb; sincosf(0.5f*(phi - om), &sb, &cb);   // em = cb + i sb
            const int pbit = 3 - q;
            const int bit  = (l >> pbit) & 1;
            const float pre = __shfl_xor(re, 1 << pbit);
            const float pim = __shfl_xor(im, 1 << pbit);
            const float sel = bit ? 1.f : -1.f;
            // own coef: bit? U11 : U00 ; partner coef: bit? U10 : U01
            const float coR = ca*ct;
            const float coI = sel*sa*ct;
            const float cpR = sel*cb*st;
            const float cpI = -sb*st;
            const float nr = coR*re - coI*im + cpR*pre - cpI*pim;
            const float ni = coR*im + coI*re + cpR*pim + cpI*pre;
            re = nr; im = ni;
        }
        #pragma unroll
        for (int q = 0; q < 3; ++q) {          // CNOT control=q, target=q+1
            const int cbit = 3 - q, tbit = 2 - q;
            const float sre = __shfl_xor(re, 1 << tbit);
            const float sim = __shfl_xor(im, 1 << tbit);
            if ((l >> cbit) & 1) { re = sre; im = sim; }
        }
    }
    const float pr = fmaf(re, re, im*im);
    float qo[4];
    #pragma unroll
    for (int q = 0; q < 4; ++q) {
        float v = ((l >> (3-q)) & 1) ? -pr : pr;
        v += __shfl_xor(v, 1);
        v += __shfl_xor(v, 2);
        v += __shfl_xor(v, 4);
        v += __shfl_xor(v, 8);
        qo[q] = v;
    }
    __syncthreads();

    // fc4 + log_softmax (10 lanes per row active)
    if (l < 10) {
        float z = fc4b[l];
        #pragma unroll
        for (int j = 0; j < 16; ++j) z = fmaf(fs[r][j], fc4w[l*20 + j], z);
        #pragma unroll
        for (int j = 0; j < 4; ++j)  z = fmaf(qo[j], fc4w[l*20 + 16 + j], z);
        zs[r][l] = z;
        float mx = zs[r][0];
        #pragma unroll
        for (int j = 1; j < 10; ++j) mx = fmaxf(mx, zs[r][j]);
        float se = 0.f;
        #pragma unroll
        for (int j = 0; j < 10; ++j) se += expf(zs[r][j] - mx);
        out[(size_t)(b0 + r)*10 + l] = z - mx - logf(se);
    }
}

// ---------------------------------------------------------------------------
// Fallback: round-6 monolithic kernel (used only if ws too small). Verified.
// ---------------------------------------------------------------------------
__global__ __launch_bounds__(256) void k_fused_mono(
    const float* __restrict__ x,
    const float* __restrict__ c1w, const float* __restrict__ c1b,
    const float* __restrict__ c2w, const float* __restrict__ c2b,
    const float* __restrict__ fc1w, const float* __restrict__ fc1b,
    const float* __restrict__ fc2w, const float* __restrict__ fc2b,
    const float* __restrict__ fc3w, const float* __restrict__ fc3b,
    const float* __restrict__ qw,
    const float* __restrict__ fc4w, const float* __restrict__ fc4b,
    float* __restrict__ out)
{
    __shared__ __align__(16) float p1[32*288];
    __shared__ __align__(16) float p2[3136];
    __shared__ float h1s[128];
    __shared__ float h2s[64];
    __shared__ float fts[16];

    const int b = blockIdx.x, t = threadIdx.x;
    const int lane = t & 63, wv = t >> 6;
    const int p  = lane < 49 ? lane : 48;
    const int py = p / 7, px = p % 7;

    for (int i = t; i < 9216; i += 256) p1[i] = 0.f;
    float* img = p2;
    for (int i = t; i < 900; i += 256) img[i] = 0.f;
    __syncthreads();
    const float* xi = x + (size_t)b * 784;
    for (int i = t; i < 784; i += 256)
        img[(i/28 + 1)*30 + (i%28 + 1)] = xi[i];
    __syncthreads();

    {
        const int ocb1 = __builtin_amdgcn_readfirstlane(wv*8);
        float wk[8][9], bv[8];
        #pragma unroll
        for (int o = 0; o < 8; ++o) {
            bv[o] = c1b[ocb1 + o];
            #pragma unroll
            for (int k = 0; k < 9; ++k) wk[o][k] = c1w[(ocb1 + o)*9 + k];
        }
        #pragma unroll
        for (int ch = 0; ch < 4; ++ch) {
            int pos = ch*64 + lane;
            const bool act = pos < 196;
            if (!act) pos = 195;
            const int qy = pos / 14, qx = pos % 14;
            const float* ib = img + (2*qy)*30 + 2*qx;
            float v[4][4];
            #pragma unroll
            for (int rr = 0; rr < 4; ++rr) {
                const float2 a = *(const float2*)(ib + rr*30);
                const float2 c = *(const float2*)(ib + rr*30 + 2);
                v[rr][0]=a.x; v[rr][1]=a.y; v[rr][2]=c.x; v[rr][3]=c.y;
            }
            #pragma unroll
            for (int o = 0; o < 8; ++o) {
                float m = 0.f;
                #pragma unroll
                for (int dy = 0; dy < 2; ++dy)
                #pragma unroll
                for (int dx = 0; dx < 2; ++dx) {
                    float acc = bv[o];
                    #pragma unroll
                    for (int ky = 0; ky < 3; ++ky)
                    #pragma unroll
                    for (int kx = 0; kx < 3; ++kx)
                        acc = fmaf(v[dy+ky][dx+kx], wk[o][ky*3+kx], acc);
                    m = fmaxf(m, acc);
                }
                if (act) p1[(ocb1 + o)*288 + (qy+1)*18 + (qx+1)] = m;
            }
        }
    }
    __syncthreads();

    for (int g = 0; g < 2; ++g) {
        const int ocb = __builtin_amdgcn_readfirstlane(g*32 + wv*8);
        float acc[8][2][2];
        #pragma unroll
        for (int o = 0; o < 8; ++o) {
            const float bvv = c2b[ocb + o];
            acc[o][0][0]=bvv; acc[o][0][1]=bvv; acc[o][1][0]=bvv; acc[o][1][1]=bvv;
        }
        #pragma unroll 4
        for (int ic = 0; ic < 32; ++ic) {
            const float* pp = p1 + ic*288 + (2*py)*18 + 2*px;
            float v[4][4];
            #pragma unroll
            for (int rr = 0; rr < 4; ++rr) {
                const float2 a = *(const float2*)(pp + rr*18);
                const float2 c = *(const float2*)(pp + rr*18 + 2);
                v[rr][0]=a.x; v[rr][1]=a.y; v[rr][2]=c.x; v[rr][3]=c.y;
            }
            const float* wb = c2w + (size_t)ocb*288 + ic*9;
            #pragma unroll
            for (int o = 0; o < 8; ++o) {
                float wk2[9];
                #pragma unroll
                for (int k = 0; k < 9; ++k) wk2[k] = wb[o*288 + k];
                #pragma unroll
                for (int dy = 0; dy < 2; ++dy)
                #pragma unroll
                for (int dx = 0; dx < 2; ++dx)
                    #pragma unroll
                    for (int ky = 0; ky < 3; ++ky)
                    #pragma unroll
                    for (int kx = 0; kx < 3; ++kx)
                        acc[o][dy][dx] = fmaf(v[dy+ky][dx+kx], wk2[ky*3+kx],
                                              acc[o][dy][dx]);
            }
        }
        if (lane < 49) {
            #pragma unroll
            for (int o = 0; o < 8; ++o) {
                const float mx = fmaxf(fmaxf(acc[o][0][0], acc[o][0][1]),
                                       fmaxf(acc[o][1][0], acc[o][1][1]));
                p2[(ocb + o)*49 + p] = fmaxf(mx, 0.f);
            }
        }
    }
    __syncthreads();

    for (int pass = 0; pass < 8; ++pass) {
        const int o = wv*32 + pass*4;
        const float* w0 = fc1w + (size_t)o*3136;
        float a0=0.f, a1=0.f, a2=0.f, a3=0.f;
        for (int kb = 0; kb < 3072; kb += 256) {
            const int k = kb + lane*4;
            const float4 pv = *(const float4*)&p2[k];
            const float4 q0 = *(const float4*)(w0 + k);
            const float4 q1 = *(const float4*)(w0 + 3136 + k);
            const float4 q2 = *(const float4*)(w0 + 6272 + k);
            const float4 q3 = *(const float4*)(w0 + 9408 + k);
            a0 = fmaf(pv.x,q0.x,fmaf(pv.y,q0.y,fmaf(pv.z,q0.z,fmaf(pv.w,q0.w,a0))));
            a1 = fmaf(pv.x,q1.x,fmaf(pv.y,q1.y,fmaf(pv.z,q1.z,fmaf(pv.w,q1.w,a1))));
            a2 = fmaf(pv.x,q2.x,fmaf(pv.y,q2.y,fmaf(pv.z,q2.z,fmaf(pv.w,q2.w,a2))));
            a3 = fmaf(pv.x,q3.x,fmaf(pv.y,q3.y,fmaf(pv.z,q3.z,fmaf(pv.w,q3.w,a3))));
        }
        if (lane < 16) {
            const int k = 3072 + lane*4;
            const float4 pv = *(const float4*)&p2[k];
            const float4 q0 = *(const float4*)(w0 + k);
            const float4 q1 = *(const float4*)(w0 + 3136 + k);
            const float4 q2 = *(const float4*)(w0 + 6272 + k);
            const float4 q3 = *(const float4*)(w0 + 9408 + k);
            a0 = fmaf(pv.x,q0.x,fmaf(pv.y,q0.y,fmaf(pv.z,q0.z,fmaf(pv.w,q0.w,a0))));
            a1 = fmaf(pv.x,q1.x,fmaf(pv.y,q1.y,fmaf(pv.z,q1.z,fmaf(pv.w,q1.w,a1))));
            a2 = fmaf(pv.x,q2.x,fmaf(pv.y,q2.y,fmaf(pv.z,q2.z,fmaf(pv.w,q2.w,a2))));
            a3 = fmaf(pv.x,q3.x,fmaf(pv.y,q3.y,fmaf(pv.w,q3.z,fmaf(pv.w,q3.w,a3))));
        }
        #pragma unroll
        for (int s = 1; s < 64; s <<= 1) {
            a0 += __shfl_xor(a0, s);
            a1 += __shfl_xor(a1, s);
            a2 += __shfl_xor(a2, s);
            a3 += __shfl_xor(a3, s);
        }
        if (lane == ((o+0)&63)) h1s[o+0] = fmaxf(a0 + fc1b[o+0], 0.f);
        if (lane == ((o+1)&63)) h1s[o+1] = fmaxf(a1 + fc1b[o+1], 0.f);
        if (lane == ((o+2)&63)) h1s[o+2] = fmaxf(a2 + fc1b[o+2], 0.f);
        if (lane == ((o+3)&63)) h1s[o+3] = fmaxf(a3 + fc1b[o+3], 0.f);
    }
    __syncthreads();

    if (t < 64) {
        float a = fc2b[t];
        const float* wr = fc2w + t * 128;
        for (int k = 0; k < 128; ++k) a = fmaf(h1s[k], wr[k], a);
        h2s[t] = fmaxf(a, 0.f);
    }
    __syncthreads();
    if (t < 16) {
        float a = fc3b[t];
        const float* wr = fc3w + t * 64;
        for (int k = 0; k < 64; ++k) a = fmaf(h2s[k], wr[k], a);
        fts[t] = fmaxf(a, 0.f);
    }
    __syncthreads();

    if (t == 0) {
        float feat[16];
        #pragma unroll
        for (int j = 0; j < 16; ++j) feat[j] = fts[j];
        float nrm2 = 0.f;
        #pragma unroll
        for (int j = 0; j < 16; ++j) nrm2 += feat[j]*feat[j];
        const float inv = 1.f / fmaxf(sqrtf(nrm2), 1e-12f);
        float ar[16], ai[16];
        #pragma unroll
        for (int j = 0; j < 16; ++j) { ar[j] = feat[j]*inv; ai[j] = 0.f; }
        #pragma unroll
        for (int layer = 0; layer < 2; ++layer) {
            #pragma unroll
            for (int q = 0; q < 4; ++q) {
                const float phi = qw[(layer*4 + q)*3 + 0];
                const float th  = qw[(layer*4 + q)*3 + 1];
                const float om  = qw[(layer*4 + q)*3 + 2];
                float st, ct; sincosf(0.5f*th, &st, &ct);
                float sa, ca; sincosf(0.5f*(phi + om), &sa, &ca);
                float sb, cb; sincosf(0.5f*(phi - om), &sb, &cb);
                const float U00r =  ca*ct, U00i = -sa*ct;
                const float U01r = -cb*st, U01i = -sb*st;
                const float U10r =  cb*st, U10i = -sb*st;
                const float U11r =  ca*ct, U11i =  sa*ct;
                const int stride = 1 << (3 - q);
                #pragma unroll
                for (int i0 = 0; i0 < 16; ++i0) {
                    if (i0 & stride) continue;
                    const int i1 = i0 | stride;
                    const float r0 = ar[i0], m0 = ai[i0];
                    const float r1 = ar[i1], m1 = ai[i1];
                    ar[i0] = U00r*r0 - U00i*m0 + U01r*r1 - U01i*m1;
                    ai[i0] = U00r*m0 + U00i*r0 + U01r*m1 + U01i*r1;
                    ar[i1] = U10r*r0 - U10i*m0 + U11r*r1 - U11i*m1;
                    ai[i1] = U10r*m0 + U10i*r0 + U11r*m1 + U11i*r1;
                }
            }
            #pragma unroll
            for (int q = 0; q < 3; ++q) {
                const int cbit = 1 << (3 - q), tbit = 1 << (2 - q);
                #pragma unroll
                for (int idx = 0; idx < 16; ++idx) {
                    if ((idx & cbit) && !(idx & tbit)) {
                        const int j = idx | tbit;
                        float tr = ar[idx]; ar[idx] = ar[j]; ar[j] = tr;
                        float ti = ai[idx]; ai[idx] = ai[j]; ai[j] = ti;
                    }
                }
            }
        }
        float qo[4];
        #pragma unroll
        for (int q = 0; q < 4; ++q) {
            const int pb = 1 << (3 - q);
            float s = 0.f;
            #pragma unroll
            for (int idx = 0; idx < 16; ++idx) {
                const float pv = ar[idx]*ar[idx] + ai[idx]*ai[idx];
                s += (idx & pb) ? -pv : pv;
            }
            qo[q] = s;
        }
        float z[10];
        float mx = -1e30f;
        #pragma unroll
        for (int o = 0; o < 10; ++o) {
            float a = fc4b[o];
            #pragma unroll
            for (int j = 0; j < 16; ++j) a = fmaf(feat[j], fc4w[o*20 + j], a);
            #pragma unroll
            for (int j = 0; j < 4;  ++j) a = fmaf(qo[j],  fc4w[o*20 + 16 + j], a);
            z[o] = a; mx = fmaxf(mx, a);
        }
        float se = 0.f;
        #pragma unroll
        for (int o = 0; o < 10; ++o) se += expf(z[o] - mx);
        const float lse = logf(se);
        #pragma unroll
        for (int o = 0; o < 10; ++o) out[(size_t)b*10 + o] = z[o] - mx - lse;
    }
}

// ---------------------------------------------------------------------------
extern "C" void kernel_launch(void* const* d_in, const int* in_sizes, int n_in,
                              void* d_out, int out_size, void* d_ws, size_t ws_size,
                              hipStream_t stream) {
    const float* x     = (const float*)d_in[0];
    const float* c1w   = (const float*)d_in[1];
    const float* c1b   = (const float*)d_in[2];
    const float* c2w   = (const float*)d_in[3];
    const float* c2b   = (const float*)d_in[4];
    const float* fc1w  = (const float*)d_in[5];
    const float* fc1b  = (const float*)d_in[6];
    const float* fc2w  = (const float*)d_in[7];
    const float* fc2b  = (const float*)d_in[8];
    const float* fc3w  = (const float*)d_in[9];
    const float* fc3b  = (const float*)d_in[10];
    const float* qwp   = (const float*)d_in[11];
    const float* fc4w  = (const float*)d_in[12];
    const float* fc4b  = (const float*)d_in[13];
    float* outp = (float*)d_out;

    if (ws_size >= 1024u*128u*sizeof(float)) {
        float* h1g = (float*)d_ws;                 // 512 KB
        k_body<<<1024, 256, 0, stream>>>(x, c1w, c1b, c2w, c2b, fc1w, fc1b, h1g);
        k_head<<<64, 256, 0, stream>>>(h1g, fc2w, fc2b, fc3w, fc3b, qwp,
                                       fc4w, fc4b, outp);
    } else {
        k_fused_mono<<<1024, 256, 0, stream>>>(x, c1w, c1b, c2w, c2b, fc1w, fc1b,
                                               fc2w, fc2b, fc3w, fc3b, qwp,
                                               fc4w, fc4b, outp);
    }
}

// Round 8
// 174.927 us; speedup vs baseline: 1.1044x; 1.1044x over previous
//
#include <hip/hip_runtime.h>
#include <math.h>

// ---------------------------------------------------------------------------
// Fully fused QFNN forward, ONE block (256 thr) per image. Round 8:
// = round 6 monolith, but conv2 does all 16 oc/wave in ONE pass over p1
// (halves conv2 LDS reads + bank-conflict cycles; doubles acc ILP).
// ---------------------------------------------------------------------------
__global__ __launch_bounds__(256) void k_fused(
    const float* __restrict__ x,
    const float* __restrict__ c1w, const float* __restrict__ c1b,
    const float* __restrict__ c2w, const float* __restrict__ c2b,
    const float* __restrict__ fc1w, const float* __restrict__ fc1b,
    const float* __restrict__ fc2w, const float* __restrict__ fc2b,
    const float* __restrict__ fc3w, const float* __restrict__ fc3b,
    const float* __restrict__ qw,
    const float* __restrict__ fc4w, const float* __restrict__ fc4b,
    float* __restrict__ out)
{
    __shared__ __align__(16) float p1[32*288];   // [ic][16 rows][18 cols], zero border
    __shared__ __align__(16) float p2[3136];     // union: img(900) during conv1, then p2
    __shared__ float h1s[128];
    __shared__ float h2s[64];
    __shared__ float fts[16];

    const int b = blockIdx.x, t = threadIdx.x;
    const int lane = t & 63, wv = t >> 6;
    const int p  = lane < 49 ? lane : 48;        // conv2 pooled position (7x7)
    const int py = p / 7, px = p % 7;

    for (int i = t; i < 9216; i += 256) p1[i] = 0.f;
    float* img = p2;                              // 30x30 padded, stride 30
    for (int i = t; i < 900; i += 256) img[i] = 0.f;
    __syncthreads();
    const float* xi = x + (size_t)b * 784;
    for (int i = t; i < 784; i += 256)
        img[(i/28 + 1)*30 + (i%28 + 1)] = xi[i];
    __syncthreads();

    // ---- conv1 (1->32) + ReLU + maxpool2 -> p1 ----
    // wave -> 8 oc; lane covers 4 of the 196 pooled positions (14x14).
    {
        const int ocb1 = __builtin_amdgcn_readfirstlane(wv*8);
        float wk[8][9], bv[8];
        #pragma unroll
        for (int o = 0; o < 8; ++o) {
            bv[o] = c1b[ocb1 + o];
            #pragma unroll
            for (int k = 0; k < 9; ++k) wk[o][k] = c1w[(ocb1 + o)*9 + k];
        }
        #pragma unroll
        for (int ch = 0; ch < 4; ++ch) {
            int pos = ch*64 + lane;
            const bool act = pos < 196;
            if (!act) pos = 195;
            const int qy = pos / 14, qx = pos % 14;
            const float* ib = img + (2*qy)*30 + 2*qx;
            float v[4][4];
            #pragma unroll
            for (int rr = 0; rr < 4; ++rr) {
                const float2 a = *(const float2*)(ib + rr*30);
                const float2 c = *(const float2*)(ib + rr*30 + 2);
                v[rr][0]=a.x; v[rr][1]=a.y; v[rr][2]=c.x; v[rr][3]=c.y;
            }
            #pragma unroll
            for (int o = 0; o < 8; ++o) {
                float m = 0.f;                    // relu(max) == max(0, max)
                #pragma unroll
                for (int dy = 0; dy < 2; ++dy)
                #pragma unroll
                for (int dx = 0; dx < 2; ++dx) {
                    float acc = bv[o];
                    #pragma unroll
                    for (int ky = 0; ky < 3; ++ky)
                    #pragma unroll
                    for (int kx = 0; kx < 3; ++kx)
                        acc = fmaf(v[dy+ky][dx+kx], wk[o][ky*3+kx], acc);
                    m = fmaxf(m, acc);
                }
                if (act) p1[(ocb1 + o)*288 + (qy+1)*18 + (qx+1)] = m;
            }
        }
    }
    __syncthreads();                              // img dead after this point

    // ---- conv2 (32->64) + ReLU + maxpool2 -> p2, SINGLE pass, 16 oc/wave ----
    // Per ic: 8 ds_read_b64 (16 vals) feed 576 FMA (16 oc x 2x2 x 9).
    {
        const int ocb = __builtin_amdgcn_readfirstlane(wv*16);
        float acc[16][2][2];
        #pragma unroll
        for (int o = 0; o < 16; ++o) {
            const float bvv = c2b[ocb + o];
            acc[o][0][0]=bvv; acc[o][0][1]=bvv; acc[o][1][0]=bvv; acc[o][1][1]=bvv;
        }
        for (int ic = 0; ic < 32; ++ic) {
            const float* pp = p1 + ic*288 + (2*py)*18 + 2*px;
            float v[4][4];
            #pragma unroll
            for (int rr = 0; rr < 4; ++rr) {
                const float2 a = *(const float2*)(pp + rr*18);
                const float2 c = *(const float2*)(pp + rr*18 + 2);
                v[rr][0]=a.x; v[rr][1]=a.y; v[rr][2]=c.x; v[rr][3]=c.y;
            }
            const float* wb = c2w + (size_t)ocb*288 + ic*9;
            #pragma unroll
            for (int o = 0; o < 16; ++o) {
                float wk2[9];
                #pragma unroll
                for (int k = 0; k < 9; ++k) wk2[k] = wb[o*288 + k];
                #pragma unroll
                for (int dy = 0; dy < 2; ++dy)
                #pragma unroll
                for (int dx = 0; dx < 2; ++dx)
                    #pragma unroll
                    for (int ky = 0; ky < 3; ++ky)
                    #pragma unroll
                    for (int kx = 0; kx < 3; ++kx)
                        acc[o][dy][dx] = fmaf(v[dy+ky][dx+kx], wk2[ky*3+kx],
                                              acc[o][dy][dx]);
            }
        }
        if (lane < 49) {
            #pragma unroll
            for (int o = 0; o < 16; ++o) {
                const float mx = fmaxf(fmaxf(acc[o][0][0], acc[o][0][1]),
                                       fmaxf(acc[o][1][0], acc[o][1][1]));
                p2[(ocb + o)*49 + p] = fmaxf(mx, 0.f);
            }
        }
    }
    __syncthreads();

    // ---- fc1 (3136 -> 128) + ReLU ----
    // wave -> 32 rows (8 passes x 4 rows), lane -> k-slice; coalesced weights,
    // LDS float4 broadcast shared by 4 rows; shfl_xor reduction.
    for (int pass = 0; pass < 8; ++pass) {
        const int o = wv*32 + pass*4;
        const float* w0 = fc1w + (size_t)o*3136;
        float a0=0.f, a1=0.f, a2=0.f, a3=0.f;
        for (int kb = 0; kb < 3072; kb += 256) {
            const int k = kb + lane*4;
            const float4 pv = *(const float4*)&p2[k];
            const float4 q0 = *(const float4*)(w0 + k);
            const float4 q1 = *(const float4*)(w0 + 3136 + k);
            const float4 q2 = *(const float4*)(w0 + 6272 + k);
            const float4 q3 = *(const float4*)(w0 + 9408 + k);
            a0 = fmaf(pv.x,q0.x,fmaf(pv.y,q0.y,fmaf(pv.z,q0.z,fmaf(pv.w,q0.w,a0))));
            a1 = fmaf(pv.x,q1.x,fmaf(pv.y,q1.y,fmaf(pv.z,q1.z,fmaf(pv.w,q1.w,a1))));
            a2 = fmaf(pv.x,q2.x,fmaf(pv.y,q2.y,fmaf(pv.z,q2.z,fmaf(pv.w,q2.w,a2))));
            a3 = fmaf(pv.x,q3.x,fmaf(pv.y,q3.y,fmaf(pv.z,q3.z,fmaf(pv.w,q3.w,a3))));
        }
        if (lane < 16) {                           // tail 3072..3135
            const int k = 3072 + lane*4;
            const float4 pv = *(const float4*)&p2[k];
            const float4 q0 = *(const float4*)(w0 + k);
            const float4 q1 = *(const float4*)(w0 + 3136 + k);
            const float4 q2 = *(const float4*)(w0 + 6272 + k);
            const float4 q3 = *(const float4*)(w0 + 9408 + k);
            a0 = fmaf(pv.x,q0.x,fmaf(pv.y,q0.y,fmaf(pv.z,q0.z,fmaf(pv.w,q0.w,a0))));
            a1 = fmaf(pv.x,q1.x,fmaf(pv.y,q1.y,fmaf(pv.z,q1.z,fmaf(pv.w,q1.w,a1))));
            a2 = fmaf(pv.x,q2.x,fmaf(pv.y,q2.y,fmaf(pv.z,q2.z,fmaf(pv.w,q2.w,a2))));
            a3 = fmaf(pv.x,q3.x,fmaf(pv.y,q3.y,fmaf(pv.z,q3.z,fmaf(pv.w,q3.w,a3))));
        }
        #pragma unroll
        for (int s = 1; s < 64; s <<= 1) {
            a0 += __shfl_xor(a0, s);
            a1 += __shfl_xor(a1, s);
            a2 += __shfl_xor(a2, s);
            a3 += __shfl_xor(a3, s);
        }
        if (lane == ((o+0)&63)) h1s[o+0] = fmaxf(a0 + fc1b[o+0], 0.f);
        if (lane == ((o+1)&63)) h1s[o+1] = fmaxf(a1 + fc1b[o+1], 0.f);
        if (lane == ((o+2)&63)) h1s[o+2] = fmaxf(a2 + fc1b[o+2], 0.f);
        if (lane == ((o+3)&63)) h1s[o+3] = fmaxf(a3 + fc1b[o+3], 0.f);
    }
    __syncthreads();

    // ---- fc2 (128 -> 64) + ReLU ----
    if (t < 64) {
        float a = fc2b[t];
        const float* wr = fc2w + t * 128;
        for (int k = 0; k < 128; ++k) a = fmaf(h1s[k], wr[k], a);
        h2s[t] = fmaxf(a, 0.f);
    }
    __syncthreads();

    // ---- fc3 (64 -> 16) + ReLU ----
    if (t < 16) {
        float a = fc3b[t];
        const float* wr = fc3w + t * 64;
        for (int k = 0; k < 64; ++k) a = fmaf(h2s[k], wr[k], a);
        fts[t] = fmaxf(a, 0.f);
    }
    __syncthreads();

    // ---- quantum circuit + fc4 + log_softmax: serial on thread 0 (verified) ----
    if (t == 0) {
        float feat[16];
        #pragma unroll
        for (int j = 0; j < 16; ++j) feat[j] = fts[j];

        float nrm2 = 0.f;
        #pragma unroll
        for (int j = 0; j < 16; ++j) nrm2 += feat[j]*feat[j];
        const float inv = 1.f / fmaxf(sqrtf(nrm2), 1e-12f);
        float ar[16], ai[16];
        #pragma unroll
        for (int j = 0; j < 16; ++j) { ar[j] = feat[j]*inv; ai[j] = 0.f; }

        #pragma unroll
        for (int layer = 0; layer < 2; ++layer) {
            #pragma unroll
            for (int q = 0; q < 4; ++q) {
                const float phi = qw[(layer*4 + q)*3 + 0];
                const float th  = qw[(layer*4 + q)*3 + 1];
                const float om  = qw[(layer*4 + q)*3 + 2];
                float st, ct; sincosf(0.5f*th, &st, &ct);
                float sa, ca; sincosf(0.5f*(phi + om), &sa, &ca); // ep = ca - i sa
                float sb, cb; sincosf(0.5f*(phi - om), &sb, &cb); // em = cb + i sb
                const float U00r =  ca*ct, U00i = -sa*ct;
                const float U01r = -cb*st, U01i = -sb*st;
                const float U10r =  cb*st, U10i = -sb*st;
                const float U11r =  ca*ct, U11i =  sa*ct;
                const int stride = 1 << (3 - q);
                #pragma unroll
                for (int i0 = 0; i0 < 16; ++i0) {
                    if (i0 & stride) continue;
                    const int i1 = i0 | stride;
                    const float r0 = ar[i0], m0 = ai[i0];
                    const float r1 = ar[i1], m1 = ai[i1];
                    ar[i0] = U00r*r0 - U00i*m0 + U01r*r1 - U01i*m1;
                    ai[i0] = U00r*m0 + U00i*r0 + U01r*m1 + U01i*r1;
                    ar[i1] = U10r*r0 - U10i*m0 + U11r*r1 - U11i*m1;
                    ai[i1] = U10r*m0 + U10i*r0 + U11r*m1 + U11i*r1;
                }
            }
            #pragma unroll
            for (int q = 0; q < 3; ++q) {   // CNOT control=q, target=q+1
                const int cbit = 1 << (3 - q), tbit = 1 << (2 - q);
                #pragma unroll
                for (int idx = 0; idx < 16; ++idx) {
                    if ((idx & cbit) && !(idx & tbit)) {
                        const int j = idx | tbit;
                        float tr = ar[idx]; ar[idx] = ar[j]; ar[j] = tr;
                        float ti = ai[idx]; ai[idx] = ai[j]; ai[j] = ti;
                    }
                }
            }
        }

        float qo[4];
        #pragma unroll
        for (int q = 0; q < 4; ++q) {
            const int pb = 1 << (3 - q);
            float s = 0.f;
            #pragma unroll
            for (int idx = 0; idx < 16; ++idx) {
                const float pv = ar[idx]*ar[idx] + ai[idx]*ai[idx];
                s += (idx & pb) ? -pv : pv;
            }
            qo[q] = s;
        }

        float z[10];
        float mx = -1e30f;
        #pragma unroll
        for (int o = 0; o < 10; ++o) {
            float a = fc4b[o];
            #pragma unroll
            for (int j = 0; j < 16; ++j) a = fmaf(feat[j], fc4w[o*20 + j], a);
            #pragma unroll
            for (int j = 0; j < 4;  ++j) a = fmaf(qo[j],  fc4w[o*20 + 16 + j], a);
            z[o] = a; mx = fmaxf(mx, a);
        }
        float se = 0.f;
        #pragma unroll
        for (int o = 0; o < 10; ++o) se += expf(z[o] - mx);
        const float lse = logf(se);
        #pragma unroll
        for (int o = 0; o < 10; ++o) out[(size_t)b*10 + o] = z[o] - mx - lse;
    }
}

// ---------------------------------------------------------------------------
extern "C" void kernel_launch(void* const* d_in, const int* in_sizes, int n_in,
                              void* d_out, int out_size, void* d_ws, size_t ws_size,
                              hipStream_t stream) {
    const float* x     = (const float*)d_in[0];
    const float* c1w   = (const float*)d_in[1];
    const float* c1b   = (const float*)d_in[2];
    const float* c2w   = (const float*)d_in[3];
    const float* c2b   = (const float*)d_in[4];
    const float* fc1w  = (const float*)d_in[5];
    const float* fc1b  = (const float*)d_in[6];
    const float* fc2w  = (const float*)d_in[7];
    const float* fc2b  = (const float*)d_in[8];
    const float* fc3w  = (const float*)d_in[9];
    const float* fc3b  = (const float*)d_in[10];
    const float* qwp   = (const float*)d_in[11];
    const float* fc4w  = (const float*)d_in[12];
    const float* fc4b  = (const float*)d_in[13];
    float* outp = (float*)d_out;

    k_fused<<<1024, 256, 0, stream>>>(x, c1w, c1b, c2w, c2b, fc1w, fc1b,
                                      fc2w, fc2b, fc3w, fc3b, qwp, fc4w, fc4b,
                                      outp);
}

// Round 9
// 108.974 us; speedup vs baseline: 1.7728x; 1.6052x over previous
//
#include <hip/hip_runtime.h>
#include <math.h>

typedef unsigned short ushort_t;
typedef unsigned int uint_t;
typedef __attribute__((ext_vector_type(8))) short short8v;   // 8 bf16 = 4 VGPR
typedef __attribute__((ext_vector_type(4))) float float4v;   // MFMA accum

static __device__ __forceinline__ ushort_t f2bf(float f) {
    union { float f; uint_t u; } v; v.f = f;
    uint_t r = (v.u + 0x7FFFu + ((v.u >> 16) & 1u)) >> 16;   // RNE
    return (ushort_t)r;
}

// ---------------------------------------------------------------------------
// Fully fused QFNN forward, ONE block (256 thr) per image. Round 9:
// conv2 via bf16 MFMA (9 shift-GEMMs, M=196 quad-ordered, K=32, N=64).
// p1 stored bf16 channel-last in 4 ic-planes [4][16][16][8] (16 KB).
// conv1 / fc1 / fc2 / fc3 / circuit / fc4 / softmax: fp32, verified (round 8).
// ---------------------------------------------------------------------------
__global__ __launch_bounds__(256) void k_fused(
    const float* __restrict__ x,
    const float* __restrict__ c1w, const float* __restrict__ c1b,
    const float* __restrict__ c2w, const float* __restrict__ c2b,
    const float* __restrict__ fc1w, const float* __restrict__ fc1b,
    const float* __restrict__ fc2w, const float* __restrict__ fc2b,
    const float* __restrict__ fc3w, const float* __restrict__ fc3b,
    const float* __restrict__ qw,
    const float* __restrict__ fc4w, const float* __restrict__ fc4b,
    float* __restrict__ out)
{
    // p1cl: plane g = ic>>3; within plane: ((y*16+x)*8 + (ic&7)) bf16.
    // plane stride = 2048 ushorts (4 KB). Borders (y,x = 0 or 15) are zero.
    __shared__ __align__(16) ushort_t p1cl[8192];            // 16 KB
    __shared__ __align__(16) float p2[3136];                 // union: img(900) then p2
    __shared__ float h1s[128];
    __shared__ float h2s[64];
    __shared__ float fts[16];

    const int b = blockIdx.x, t = threadIdx.x;
    const int lane = t & 63, wv = t >> 6;

    for (int i = t; i < 4096; i += 256) ((uint_t*)p1cl)[i] = 0u;
    float* img = p2;                                          // 30x30 padded
    for (int i = t; i < 900; i += 256) img[i] = 0.f;
    __syncthreads();
    const float* xi = x + (size_t)b * 784;
    for (int i = t; i < 784; i += 256)
        img[(i/28 + 1)*30 + (i%28 + 1)] = xi[i];
    __syncthreads();

    // ---- conv1 (1->32) + ReLU + maxpool2 -> p1cl (bf16, plane = wv) ----
    {
        const int ocb1 = wv*8;                                // plane wv holds ic wv*8..+7
        float wk[8][9], bv[8];
        #pragma unroll
        for (int o = 0; o < 8; ++o) {
            bv[o] = c1b[ocb1 + o];
            #pragma unroll
            for (int k = 0; k < 9; ++k) wk[o][k] = c1w[(ocb1 + o)*9 + k];
        }
        #pragma unroll
        for (int ch = 0; ch < 4; ++ch) {
            int pos = ch*64 + lane;
            const bool act = pos < 196;
            if (!act) pos = 195;
            const int qy = pos / 14, qx = pos % 14;
            const float* ib = img + (2*qy)*30 + 2*qx;
            float v[4][4];
            #pragma unroll
            for (int rr = 0; rr < 4; ++rr) {
                const float2 a = *(const float2*)(ib + rr*30);
                const float2 c = *(const float2*)(ib + rr*30 + 2);
                v[rr][0]=a.x; v[rr][1]=a.y; v[rr][2]=c.x; v[rr][3]=c.y;
            }
            short8v pk;
            #pragma unroll
            for (int o = 0; o < 8; ++o) {
                float m = 0.f;                                // relu(max)==max(0,max)
                #pragma unroll
                for (int dy = 0; dy < 2; ++dy)
                #pragma unroll
                for (int dx = 0; dx < 2; ++dx) {
                    float acc = bv[o];
                    #pragma unroll
                    for (int ky = 0; ky < 3; ++ky)
                    #pragma unroll
                    for (int kx = 0; kx < 3; ++kx)
                        acc = fmaf(v[dy+ky][dx+kx], wk[o][ky*3+kx], acc);
                    m = fmaxf(m, acc);
                }
                pk[o] = (short)f2bf(m);
            }
            if (act)
                *(short8v*)&p1cl[wv*2048 + ((qy+1)*16 + (qx+1))*8] = pk;
        }
    }
    __syncthreads();                                          // img dead now

    // ---- conv2 (32->64) + ReLU + maxpool2 via MFMA -> p2 ----
    // Wave wv owns oc-tile ocb = wv*16. A-row r (0..195): quad q=r>>2,
    // (dy,dx)=((r>>1)&1, r&1), conv coords y0=2(q/7)+dy, x0=2(q%7)+dx.
    // A[r][ic] = p1cl[(y0+ky)*16 + (x0+kx)][ic] (border gives SAME padding).
    // C layout: col(oc)=lane&15, row=(lane>>4)*4+reg -> regs = one pool quad.
    {
        const int ocb = wv*16;
        const int col = lane & 15, g = lane >> 4;
        const int oc  = ocb + col;
        short8v bfr[9];                                       // B frags, 9 shifts
        #pragma unroll
        for (int j = 0; j < 8; ++j) {
            const float* wp = c2w + ((size_t)oc*32 + g*8 + j)*9;
            #pragma unroll
            for (int s = 0; s < 9; ++s) bfr[s][j] = (short)f2bf(wp[s]);
        }
        const float bv = c2b[oc];
        #pragma unroll 1
        for (int mt = 0; mt < 13; ++mt) {
            int row = mt*16 + col; if (row > 195) row = 195;
            const int q  = row >> 2;
            const int py = q / 7, px = q - py*7;
            const int y0 = 2*py + ((row>>1)&1), x0 = 2*px + (row&1);
            const ushort_t* ap = &p1cl[g*2048 + (y0*16 + x0)*8];
            float4v c0 = {bv, bv, bv, bv};
            float4v c1 = {0.f, 0.f, 0.f, 0.f};
            // shift s=ky*3+kx -> ushort offset ky*128 + kx*8 (imm-foldable)
            c0 = __builtin_amdgcn_mfma_f32_16x16x32_bf16(*(const short8v*)(ap +   0), bfr[0], c0, 0, 0, 0);
            c1 = __builtin_amdgcn_mfma_f32_16x16x32_bf16(*(const short8v*)(ap +   8), bfr[1], c1, 0, 0, 0);
            c0 = __builtin_amdgcn_mfma_f32_16x16x32_bf16(*(const short8v*)(ap +  16), bfr[2], c0, 0, 0, 0);
            c1 = __builtin_amdgcn_mfma_f32_16x16x32_bf16(*(const short8v*)(ap + 128), bfr[3], c1, 0, 0, 0);
            c0 = __builtin_amdgcn_mfma_f32_16x16x32_bf16(*(const short8v*)(ap + 136), bfr[4], c0, 0, 0, 0);
            c1 = __builtin_amdgcn_mfma_f32_16x16x32_bf16(*(const short8v*)(ap + 144), bfr[5], c1, 0, 0, 0);
            c0 = __builtin_amdgcn_mfma_f32_16x16x32_bf16(*(const short8v*)(ap + 256), bfr[6], c0, 0, 0, 0);
            c1 = __builtin_amdgcn_mfma_f32_16x16x32_bf16(*(const short8v*)(ap + 264), bfr[7], c1, 0, 0, 0);
            c0 = __builtin_amdgcn_mfma_f32_16x16x32_bf16(*(const short8v*)(ap + 272), bfr[8], c0, 0, 0, 0);
            const int quad = mt*4 + g;
            if (quad < 49) {
                const float m0 = fmaxf(fmaxf(c0[0]+c1[0], c0[1]+c1[1]),
                                       fmaxf(c0[2]+c1[2], c0[3]+c1[3]));
                p2[oc*49 + quad] = fmaxf(m0, 0.f);
            }
        }
    }
    __syncthreads();

    // ---- fc1 (3136 -> 128) + ReLU (fp32, verified) ----
    for (int pass = 0; pass < 8; ++pass) {
        const int o = wv*32 + pass*4;
        const float* w0 = fc1w + (size_t)o*3136;
        float a0=0.f, a1=0.f, a2=0.f, a3=0.f;
        for (int kb = 0; kb < 3072; kb += 256) {
            const int k = kb + lane*4;
            const float4 pv = *(const float4*)&p2[k];
            const float4 q0 = *(const float4*)(w0 + k);
            const float4 q1 = *(const float4*)(w0 + 3136 + k);
            const float4 q2 = *(const float4*)(w0 + 6272 + k);
            const float4 q3 = *(const float4*)(w0 + 9408 + k);
            a0 = fmaf(pv.x,q0.x,fmaf(pv.y,q0.y,fmaf(pv.z,q0.z,fmaf(pv.w,q0.w,a0))));
            a1 = fmaf(pv.x,q1.x,fmaf(pv.y,q1.y,fmaf(pv.z,q1.z,fmaf(pv.w,q1.w,a1))));
            a2 = fmaf(pv.x,q2.x,fmaf(pv.y,q2.y,fmaf(pv.z,q2.z,fmaf(pv.w,q2.w,a2))));
            a3 = fmaf(pv.x,q3.x,fmaf(pv.y,q3.y,fmaf(pv.z,q3.z,fmaf(pv.w,q3.w,a3))));
        }
        if (lane < 16) {                                      // tail 3072..3135
            const int k = 3072 + lane*4;
            const float4 pv = *(const float4*)&p2[k];
            const float4 q0 = *(const float4*)(w0 + k);
            const float4 q1 = *(const float4*)(w0 + 3136 + k);
            const float4 q2 = *(const float4*)(w0 + 6272 + k);
            const float4 q3 = *(const float4*)(w0 + 9408 + k);
            a0 = fmaf(pv.x,q0.x,fmaf(pv.y,q0.y,fmaf(pv.z,q0.z,fmaf(pv.w,q0.w,a0))));
            a1 = fmaf(pv.x,q1.x,fmaf(pv.y,q1.y,fmaf(pv.z,q1.z,fmaf(pv.w,q1.w,a1))));
            a2 = fmaf(pv.x,q2.x,fmaf(pv.y,q2.y,fmaf(pv.z,q2.z,fmaf(pv.w,q2.w,a2))));
            a3 = fmaf(pv.x,q3.x,fmaf(pv.y,q3.y,fmaf(pv.z,q3.z,fmaf(pv.w,q3.w,a3))));
        }
        #pragma unroll
        for (int s = 1; s < 64; s <<= 1) {
            a0 += __shfl_xor(a0, s);
            a1 += __shfl_xor(a1, s);
            a2 += __shfl_xor(a2, s);
            a3 += __shfl_xor(a3, s);
        }
        if (lane == ((o+0)&63)) h1s[o+0] = fmaxf(a0 + fc1b[o+0], 0.f);
        if (lane == ((o+1)&63)) h1s[o+1] = fmaxf(a1 + fc1b[o+1], 0.f);
        if (lane == ((o+2)&63)) h1s[o+2] = fmaxf(a2 + fc1b[o+2], 0.f);
        if (lane == ((o+3)&63)) h1s[o+3] = fmaxf(a3 + fc1b[o+3], 0.f);
    }
    __syncthreads();

    // ---- fc2 (128 -> 64) + ReLU ----
    if (t < 64) {
        float a = fc2b[t];
        const float* wr = fc2w + t * 128;
        for (int k = 0; k < 128; ++k) a = fmaf(h1s[k], wr[k], a);
        h2s[t] = fmaxf(a, 0.f);
    }
    __syncthreads();

    // ---- fc3 (64 -> 16) + ReLU ----
    if (t < 16) {
        float a = fc3b[t];
        const float* wr = fc3w + t * 64;
        for (int k = 0; k < 64; ++k) a = fmaf(h2s[k], wr[k], a);
        fts[t] = fmaxf(a, 0.f);
    }
    __syncthreads();

    // ---- quantum circuit + fc4 + log_softmax: serial on thread 0 (verified) ----
    if (t == 0) {
        float feat[16];
        #pragma unroll
        for (int j = 0; j < 16; ++j) feat[j] = fts[j];

        float nrm2 = 0.f;
        #pragma unroll
        for (int j = 0; j < 16; ++j) nrm2 += feat[j]*feat[j];
        const float inv = 1.f / fmaxf(sqrtf(nrm2), 1e-12f);
        float ar[16], ai[16];
        #pragma unroll
        for (int j = 0; j < 16; ++j) { ar[j] = feat[j]*inv; ai[j] = 0.f; }

        #pragma unroll
        for (int layer = 0; layer < 2; ++layer) {
            #pragma unroll
            for (int q = 0; q < 4; ++q) {
                const float phi = qw[(layer*4 + q)*3 + 0];
                const float th  = qw[(layer*4 + q)*3 + 1];
                const float om  = qw[(layer*4 + q)*3 + 2];
                float st, ct; sincosf(0.5f*th, &st, &ct);
                float sa, ca; sincosf(0.5f*(phi + om), &sa, &ca); // ep = ca - i sa
                float sb, cb; sincosf(0.5f*(phi - om), &sb, &cb); // em = cb + i sb
                const float U00r =  ca*ct, U00i = -sa*ct;
                const float U01r = -cb*st, U01i = -sb*st;
                const float U10r =  cb*st, U10i = -sb*st;
                const float U11r =  ca*ct, U11i =  sa*ct;
                const int stride = 1 << (3 - q);
                #pragma unroll
                for (int i0 = 0; i0 < 16; ++i0) {
                    if (i0 & stride) continue;
                    const int i1 = i0 | stride;
                    const float r0 = ar[i0], m0 = ai[i0];
                    const float r1 = ar[i1], m1 = ai[i1];
                    ar[i0] = U00r*r0 - U00i*m0 + U01r*r1 - U01i*m1;
                    ai[i0] = U00r*m0 + U00i*r0 + U01r*m1 + U01i*r1;
                    ar[i1] = U10r*r0 - U10i*m0 + U11r*r1 - U11i*m1;
                    ai[i1] = U10r*m0 + U10i*r0 + U11r*m1 + U11i*r1;
                }
            }
            #pragma unroll
            for (int q = 0; q < 3; ++q) {   // CNOT control=q, target=q+1
                const int cbit = 1 << (3 - q), tbit = 1 << (2 - q);
                #pragma unroll
                for (int idx = 0; idx < 16; ++idx) {
                    if ((idx & cbit) && !(idx & tbit)) {
                        const int j = idx | tbit;
                        float tr = ar[idx]; ar[idx] = ar[j]; ar[j] = tr;
                        float ti = ai[idx]; ai[idx] = ai[j]; ai[j] = ti;
                    }
                }
            }
        }

        float qo[4];
        #pragma unroll
        for (int q = 0; q < 4; ++q) {
            const int pb = 1 << (3 - q);
            float s = 0.f;
            #pragma unroll
            for (int idx = 0; idx < 16; ++idx) {
                const float pv = ar[idx]*ar[idx] + ai[idx]*ai[idx];
                s += (idx & pb) ? -pv : pv;
            }
            qo[q] = s;
        }

        float z[10];
        float mx = -1e30f;
        #pragma unroll
        for (int o = 0; o < 10; ++o) {
            float a = fc4b[o];
            #pragma unroll
            for (int j = 0; j < 16; ++j) a = fmaf(feat[j], fc4w[o*20 + j], a);
            #pragma unroll
            for (int j = 0; j < 4;  ++j) a = fmaf(qo[j],  fc4w[o*20 + 16 + j], a);
            z[o] = a; mx = fmaxf(mx, a);
        }
        float se = 0.f;
        #pragma unroll
        for (int o = 0; o < 10; ++o) se += expf(z[o] - mx);
        const float lse = logf(se);
        #pragma unroll
        for (int o = 0; o < 10; ++o) out[(size_t)b*10 + o] = z[o] - mx - lse;
    }
}

// ---------------------------------------------------------------------------
extern "C" void kernel_launch(void* const* d_in, const int* in_sizes, int n_in,
                              void* d_out, int out_size, void* d_ws, size_t ws_size,
                              hipStream_t stream) {
    const float* x     = (const float*)d_in[0];
    const float* c1w   = (const float*)d_in[1];
    const float* c1b   = (const float*)d_in[2];
    const float* c2w   = (const float*)d_in[3];
    const float* c2b   = (const float*)d_in[4];
    const float* fc1w  = (const float*)d_in[5];
    const float* fc1b  = (const float*)d_in[6];
    const float* fc2w  = (const float*)d_in[7];
    const float* fc2b  = (const float*)d_in[8];
    const float* fc3w  = (const float*)d_in[9];
    const float* fc3b  = (const float*)d_in[10];
    const float* qwp   = (const float*)d_in[11];
    const float* fc4w  = (const float*)d_in[12];
    const float* fc4b  = (const float*)d_in[13];
    float* outp = (float*)d_out;

    k_fused<<<1024, 256, 0, stream>>>(x, c1w, c1b, c2w, c2b, fc1w, fc1b,
                                      fc2w, fc2b, fc3w, fc3b, qwp, fc4w, fc4b,
                                      outp);
}